// Round 4
// baseline (5964.445 us; speedup 1.0000x reference)
//
#include <hip/hip_runtime.h>

// T=64, B=64, S=64, E=1024, D=1024, L=2
// Persistent-kernel schedule per step t (4 device-wide barriers):
//   A : gates0 = [attn_h|emb_t|h0prev](K=3072)·Wg0p^T + b0sum -> pointwise -> h0
//   B : gates1 = [h0|h1prev](K=2048)·Wg1p^T + b1sum -> pointwise -> h1
//   C': scores = h1f·ctx2 (per-b), softmax -> align ; qh = h1·WoutH^T
//   D': attn_h = tanh(qh + sum_s align*ctx3[s,b,:])
//
// Round-4 revision (L2-residency for phase-B weights):
//  - Remaining 21 MB/step fetch was Wg1p re-streamed every step: the per-XCD
//    cacheable set (Wg1p 2.1 + ctx2 1.05 + ctx3 1.0 + WoutH 0.25 = 4.4 MB)
//    was thrashed by ~2.5 MB/step of zero-reuse transients.
//  - All zero-reuse data now uses NON-TEMPORAL (evict-first) loads/stores:
//    rotated attn/h0/h1 reads, emb reads, out stores, weight preload.
//  - emb pre-converted to bf16 once (same f2bf rounding -> bit-identical),
//    halving emb traffic and removing the cvt8 VALU chain from phase A.
//  - Volatile write-through stays for cross-XCD rotated writes (coherence).
// MFMA order/pairing unchanged -> bit-identical numerics.

typedef __attribute__((ext_vector_type(8))) short bf16x8;
typedef __attribute__((ext_vector_type(4))) float f32x4;
typedef unsigned short u16;
typedef unsigned long long u64;

__device__ __forceinline__ float bf2f(u16 u) {
  return __uint_as_float(((unsigned int)u) << 16);
}
__device__ __forceinline__ u16 f2bf(float f) {
  unsigned int u = __float_as_uint(f);
  u += 0x7FFFu + ((u >> 16) & 1u);
  return (u16)(u >> 16);
}
__device__ __forceinline__ float sigmoidf_(float x) { return 1.0f / (1.0f + expf(-x)); }

// volatile (bypass) accessors for cross-XCD one-way data
__device__ __forceinline__ float ldvf(const float* p) { return *(const volatile float*)p; }
__device__ __forceinline__ void stvh(u16* p, u16 v) { *(volatile u16*)p = v; }
__device__ __forceinline__ void stvf(float* p, float v) { *(volatile float*)p = v; }

// non-temporal 16B load of bf16x8 (evict-first: no L2 pollution)
__device__ __forceinline__ bf16x8 ldnt(const u16* p) {
  f32x4 v = __builtin_nontemporal_load((const f32x4*)p);
  union { f32x4 f; bf16x8 b; } u; u.f = v; return u.b;
}

// ---------------- one-time: pack weights/context to bf16, bias sums --------
__global__ __launch_bounds__(256) void k_prep(
    const float* __restrict__ Wih0, const float* __restrict__ Whh0,
    const float* __restrict__ Wih1, const float* __restrict__ Whh1,
    const float* __restrict__ Wout, const float* __restrict__ Win,
    const float* __restrict__ ctx,
    const float* __restrict__ bih0, const float* __restrict__ bhh0,
    const float* __restrict__ bih1, const float* __restrict__ bhh1,
    u16* __restrict__ Wg0p, u16* __restrict__ Wg1p,
    u16* __restrict__ WoutCb, u16* __restrict__ WoutHb,
    u16* __restrict__ WinT, u16* __restrict__ ctxb,
    float* __restrict__ b0sum, float* __restrict__ b1sum)
{
  long i = (long)blockIdx.x * 256 + threadIdx.x;
  const long N0 = 4096L * 3072, N1 = 4096L * 2048, NM = 1024L * 1024,
             NC = 4194304L;
  if (i < N0) {  // Wg0p rows gd: [Wih0_feed | Wih0_emb | Whh0]
    long j = i / 3072, k = i % 3072;
    float v = (k < 1024) ? Wih0[j * 2048 + 1024 + k]
            : (k < 2048) ? Wih0[j * 2048 + (k - 1024)]
                         : Whh0[j * 1024 + (k - 2048)];
    Wg0p[i] = f2bf(v); return;
  }
  i -= N0;
  if (i < N1) {  // Wg1p rows gd: [Wih1 | Whh1]
    long j = i / 2048, k = i % 2048;
    float v = (k < 1024) ? Wih1[j * 1024 + k] : Whh1[j * 1024 + (k - 1024)];
    Wg1p[i] = f2bf(v); return;
  }
  i -= N1;
  if (i < NM) { long d = i >> 10, e = i & 1023; WoutCb[i] = f2bf(Wout[d * 2048 + e]); return; }
  i -= NM;
  if (i < NM) { long d = i >> 10, e = i & 1023; WoutHb[i] = f2bf(Wout[d * 2048 + 1024 + e]); return; }
  i -= NM;
  if (i < NM) { long e = i >> 10, d = i & 1023; WinT[i] = f2bf(Win[d * 1024 + e]); return; }
  i -= NM;
  if (i < NC) { ctxb[i] = f2bf(ctx[i]); return; }
  i -= NC;
  if (i < 4096) { b0sum[i] = bih0[i] + bhh0[i]; return; }
  i -= 4096;
  if (i < 4096) { b1sum[i] = bih1[i] + bhh1[i]; }
}

// ---------------- one-time: C[m][n] = sum_k A[m][k]*B[n][k], M=4096,N=1024,K=1024
__global__ __launch_bounds__(256) void k_gemm1k(
    const u16* __restrict__ A, const u16* __restrict__ Bm, u16* __restrict__ Cm)
{
  const int lane = threadIdx.x & 63, wv = threadIdx.x >> 6;
  const int quad = lane >> 4, cL = lane & 15;
  const int n0 = blockIdx.x * 64;
  const int m0 = blockIdx.y * 64 + wv * 16;
  f32x4 a0 = {0,0,0,0}, a1 = {0,0,0,0}, a2 = {0,0,0,0}, a3 = {0,0,0,0};
  const u16* ap  = A  + (size_t)(m0 + cL) * 1024 + quad * 8;
  const u16* bp0 = Bm + (size_t)(n0 +  0 + cL) * 1024 + quad * 8;
  const u16* bp1 = Bm + (size_t)(n0 + 16 + cL) * 1024 + quad * 8;
  const u16* bp2 = Bm + (size_t)(n0 + 32 + cL) * 1024 + quad * 8;
  const u16* bp3 = Bm + (size_t)(n0 + 48 + cL) * 1024 + quad * 8;
  #pragma unroll 4
  for (int kc = 0; kc < 1024; kc += 32) {
    bf16x8 a  = *(const bf16x8*)ap;  ap  += 32;
    bf16x8 b0 = *(const bf16x8*)bp0; bp0 += 32;
    bf16x8 b1 = *(const bf16x8*)bp1; bp1 += 32;
    bf16x8 b2 = *(const bf16x8*)bp2; bp2 += 32;
    bf16x8 b3 = *(const bf16x8*)bp3; bp3 += 32;
    a0 = __builtin_amdgcn_mfma_f32_16x16x32_bf16(a, b0, a0, 0, 0, 0);
    a1 = __builtin_amdgcn_mfma_f32_16x16x32_bf16(a, b1, a1, 0, 0, 0);
    a2 = __builtin_amdgcn_mfma_f32_16x16x32_bf16(a, b2, a2, 0, 0, 0);
    a3 = __builtin_amdgcn_mfma_f32_16x16x32_bf16(a, b3, a3, 0, 0, 0);
  }
  #pragma unroll
  for (int r = 0; r < 4; ++r) {
    size_t base = (size_t)(m0 + quad * 4 + r) * 1024;
    Cm[base + n0 +  0 + cL] = f2bf(a0[r]);
    Cm[base + n0 + 16 + cL] = f2bf(a1[r]);
    Cm[base + n0 + 32 + cL] = f2bf(a2[r]);
    Cm[base + n0 + 48 + cL] = f2bf(a3[r]);
  }
}

// ---------------- one-time: embB, initial slot-0 state, barrier reset ------
__global__ __launch_bounds__(256) void k_init(
    const float* __restrict__ emb, const float* __restrict__ feed0,
    const float* __restrict__ h0, const float* __restrict__ c0,
    u16* __restrict__ embB, u16* __restrict__ init0,
    float* __restrict__ cst, unsigned int* __restrict__ bar)
{
  long i = (long)blockIdx.x * 256 + threadIdx.x;
  if (i < 4194304) { embB[i] = f2bf(emb[i]); return; }   // emb -> bf16 (same rounding)
  i -= 4194304;
  if (i < 65536) { init0[i] = f2bf(feed0[i]); return; }               // attn slot0
  i -= 65536;
  if (i < 65536) { init0[65536 + i] = f2bf(h0[i]); return; }          // h0 slot0
  i -= 65536;
  if (i < 65536) { init0[131072 + i] = f2bf(h0[65536 + i]); return; } // h1 slot0
  i -= 65536;
  if (i < 131072) { cst[i] = c0[i]; return; }   // c0s,c1s contiguous
  i -= 131072;
  if (i < 4352) bar[i] = 0;   // release word + 256 arrival lines
}

// ---------------- device-wide barrier: relaxed flags, NO fences ------------
// bar[0] = release word; bar[16 + i*16] = arrival of block i.
// __syncthreads drains vmcnt(0) per wave before the arrival store, so all
// volatile (write-through) stores reached the coherence point; readers use
// bypass or cold-address loads -> no acquire-invalidate needed.
__device__ __forceinline__ void grid_barrier(unsigned int* bar, unsigned int gen,
                                             int bi) {
  __syncthreads();
  if (bi == 0) {
    if (threadIdx.x > 0) {
      while (__hip_atomic_load(&bar[16 + threadIdx.x * 16], __ATOMIC_RELAXED,
                               __HIP_MEMORY_SCOPE_AGENT) < gen)
        __builtin_amdgcn_s_sleep(1);
    }
    __syncthreads();
    if (threadIdx.x == 0)
      __hip_atomic_store(&bar[0], gen, __ATOMIC_RELAXED,
                         __HIP_MEMORY_SCOPE_AGENT);
  } else {
    if (threadIdx.x == 0) {
      __hip_atomic_store(&bar[16 + bi * 16], gen, __ATOMIC_RELAXED,
                         __HIP_MEMORY_SCOPE_AGENT);
      while (__hip_atomic_load(&bar[0], __ATOMIC_RELAXED,
                               __HIP_MEMORY_SCOPE_AGENT) < gen)
        __builtin_amdgcn_s_sleep(1);
    }
    __syncthreads();
  }
}

// ---------------- C' part 1: scores + softmax for one b --------------------
__device__ __forceinline__ void scores_softmax(
    int b, const float* __restrict__ h1f, const u16* __restrict__ ctx2,
    float* __restrict__ alignG, float* __restrict__ attnOut, int tid, float* smem)
{
  float* h1s = smem;          // [1024]
  float* red = smem + 1024;   // [256]
  for (int i = tid; i < 1024; i += 256) h1s[i] = ldvf(h1f + (size_t)b * 1024 + i);
  __syncthreads();
  {
    const int s = tid >> 2, pq = tid & 3;
    const u16* crow = ctx2 + (size_t)(s * 64 + b) * 1024 + pq * 256;  // L2-resident
    const float* hp = h1s + pq * 256;
    float part = 0.f;
    #pragma unroll 8
    for (int e = 0; e < 256; e += 4) {
      ushort4 cc = *(const ushort4*)(crow + e);
      part += hp[e] * bf2f(cc.x) + hp[e + 1] * bf2f(cc.y)
            + hp[e + 2] * bf2f(cc.z) + hp[e + 3] * bf2f(cc.w);
    }
    red[tid] = part;
  }
  __syncthreads();
  if (tid < 64) {
    float sc = red[tid * 4] + red[tid * 4 + 1] + red[tid * 4 + 2] + red[tid * 4 + 3];
    float mx = sc;
    for (int off = 32; off; off >>= 1) mx = fmaxf(mx, __shfl_xor(mx, off, 64));
    const float ex = expf(sc - mx);
    float sm = ex;
    for (int off = 32; off; off >>= 1) sm += __shfl_xor(sm, off, 64);
    const float a = ex / sm;
    stvf(alignG + b * 64 + tid, a);
    __builtin_nontemporal_store(a, attnOut + b * 64 + tid);  // external output
  }
}

// ---------------- the persistent kernel ------------------------------------
__global__ __launch_bounds__(256, 1) void k_persist(
    u16* WgRot,                       // Wg0p weights, then rotation slots (alias)
    const u16* __restrict__ Wg1p, const u16* __restrict__ WoutHb,
    const u16* __restrict__ ctx2, const u16* __restrict__ ctx3,
    const float* __restrict__ b0sum, const float* __restrict__ b1sum,
    const u16* __restrict__ embB, const u16* init0,
    float* h1f, float* c0s, float* c1s, float* qh, float* alignG,
    unsigned int* bar, float* out, float* outA)
{
  const int bi = blockIdx.x, tid = threadIdx.x;
  // XCD-aware remap: block bi sits on XCD (bi & 7); co-locate the 4 blocks
  // sharing a dg so each XCD L2 holds 1/8 of Wg1p/ctx2/ctx3/WoutH persistently.
  const int rg = (bi >> 3) & 3;
  const int dg = ((bi & 7) << 3) | (bi >> 5);
  const int w = tid >> 6, lane = tid & 63, quad = lane >> 4, cL = lane & 15;
  __shared__ float smem[1280];
  unsigned int gen = 0;

  // Rotation slot bases (overlay the Wg0p region, 3 x 64 slots x 65536 u16):
  u16* rotA  = WgRot;             // attn_h slots 1..64
  u16* rotH0 = WgRot + 4194304;   // h0 slots 1..64
  u16* rotH1 = WgRot + 8388608;   // h1 slots 1..64

  // ---- preload A-weights into registers (nt: don't seed L2) --------------
  bf16x8 wA0[48], wA1[48];
  {
    const u16* wp = WgRot + (size_t)(w * 1024 + dg * 16 + cL) * 3072 + quad * 8;
    #pragma unroll
    for (int j = 0; j < 48; ++j) {
      wA0[j] = ldnt(wp);
      wA1[j] = ldnt(wp + 32);
      wp += 64;
    }
  }
  // All preloads must complete before any block's rotation writes clobber Wg0p.
  grid_barrier(bar, ++gen, bi);

  for (int t = 0; t < 64; ++t) {
    const u16* attnR   = t ? rotA  + (size_t)(t - 1) * 65536 : init0;
    const u16* h0Rprev = t ? rotH0 + (size_t)(t - 1) * 65536 : init0 + 65536;
    const u16* h1Rprev = t ? rotH1 + (size_t)(t - 1) * 65536 : init0 + 131072;
    u16* h0W = rotH0 + (size_t)t * 65536;   // slot t+1 (written A, read B/A-next)
    u16* h1W = rotH1 + (size_t)t * 65536;   // slot t+1 (written B, read C'/B-next)
    u16* attnW = rotA + (size_t)t * 65536;  // slot t+1 (written D', read A-next)

    // ---------------- A: lstm0, weights in registers ----------------
    {
      const size_t rowOff = (size_t)(rg * 16 + cL);
      const u16* aAttn = attnR + rowOff * 1024 + quad * 8;
      const u16* aEmb = embB + (size_t)t * 65536 + rowOff * 1024 + quad * 8;
      const u16* aH0 = h0Rprev + rowOff * 1024 + quad * 8;
      f32x4 a0 = {0,0,0,0}, a1 = {0,0,0,0};
      #pragma unroll
      for (int j = 0; j < 16; ++j) {        // K 0..1023: attn_h (rotated, nt)
        bf16x8 av0 = ldnt(aAttn + j * 64);
        bf16x8 av1 = ldnt(aAttn + j * 64 + 32);
        a0 = __builtin_amdgcn_mfma_f32_16x16x32_bf16(av0, wA0[j], a0, 0, 0, 0);
        a1 = __builtin_amdgcn_mfma_f32_16x16x32_bf16(av1, wA1[j], a1, 0, 0, 0);
      }
      #pragma unroll
      for (int j = 0; j < 16; ++j) {        // K 1024..2047: emb (bf16, nt)
        bf16x8 av0 = ldnt(aEmb + j * 64);
        bf16x8 av1 = ldnt(aEmb + j * 64 + 32);
        a0 = __builtin_amdgcn_mfma_f32_16x16x32_bf16(av0, wA0[16 + j], a0, 0, 0, 0);
        a1 = __builtin_amdgcn_mfma_f32_16x16x32_bf16(av1, wA1[16 + j], a1, 0, 0, 0);
      }
      #pragma unroll
      for (int j = 0; j < 16; ++j) {        // K 2048..3071: h0prev (rotated, nt)
        bf16x8 av0 = ldnt(aH0 + j * 64);
        bf16x8 av1 = ldnt(aH0 + j * 64 + 32);
        a0 = __builtin_amdgcn_mfma_f32_16x16x32_bf16(av0, wA0[32 + j], a0, 0, 0, 0);
        a1 = __builtin_amdgcn_mfma_f32_16x16x32_bf16(av1, wA1[32 + j], a1, 0, 0, 0);
      }
      #pragma unroll
      for (int r = 0; r < 4; ++r)
        smem[w * 256 + (quad * 4 + r) * 16 + cL] = a0[r] + a1[r];
      __syncthreads();
      const int r = tid >> 4, c = tid & 15;
      const int b = rg * 16 + r, d = dg * 16 + c;
      const float gi = smem[0 * 256 + r * 16 + c] + b0sum[d];
      const float gf = smem[1 * 256 + r * 16 + c] + b0sum[1024 + d];
      const float gg = smem[2 * 256 + r * 16 + c] + b0sum[2048 + d];
      const float go = smem[3 * 256 + r * 16 + c] + b0sum[3072 + d];
      const size_t ci = (size_t)b * 1024 + d;
      const float cn = sigmoidf_(gf) * c0s[ci] + sigmoidf_(gi) * tanhf(gg);
      const float h  = sigmoidf_(go) * tanhf(cn);
      c0s[ci] = cn;                         // block-private, cached
      stvh(h0W + ci, f2bf(h));              // write-through to coherence point
    }
    grid_barrier(bar, ++gen, bi);

    // ---------------- B: lstm1, L2-resident weights -----------------
    {
      const size_t rowOff = (size_t)(rg * 16 + cL);
      const u16* a0p = h0W + rowOff * 1024 + quad * 8;       // fresh addr, nt
      const u16* a1p = h1Rprev + rowOff * 1024 + quad * 8;   // fresh addr, nt
      const u16* bp = Wg1p + (size_t)(w * 1024 + dg * 16 + cL) * 2048 + quad * 8;
      f32x4 a0 = {0,0,0,0}, a1 = {0,0,0,0};
      #pragma unroll 4
      for (int kc = 0; kc < 1024; kc += 64) {   // K 0..1023: h0 (current)
        bf16x8 av0 = ldnt(a0p);
        bf16x8 bv0 = *(const bf16x8*)bp;
        bf16x8 av1 = ldnt(a0p + 32);
        bf16x8 bv1 = *(const bf16x8*)(bp + 32);
        a0p += 64; bp += 64;
        a0 = __builtin_amdgcn_mfma_f32_16x16x32_bf16(av0, bv0, a0, 0, 0, 0);
        a1 = __builtin_amdgcn_mfma_f32_16x16x32_bf16(av1, bv1, a1, 0, 0, 0);
      }
      #pragma unroll 4
      for (int kc = 0; kc < 1024; kc += 64) {   // K 1024..2047: h1prev
        bf16x8 av0 = ldnt(a1p);
        bf16x8 bv0 = *(const bf16x8*)bp;
        bf16x8 av1 = ldnt(a1p + 32);
        bf16x8 bv1 = *(const bf16x8*)(bp + 32);
        a1p += 64; bp += 64;
        a0 = __builtin_amdgcn_mfma_f32_16x16x32_bf16(av0, bv0, a0, 0, 0, 0);
        a1 = __builtin_amdgcn_mfma_f32_16x16x32_bf16(av1, bv1, a1, 0, 0, 0);
      }
      #pragma unroll
      for (int r = 0; r < 4; ++r)
        smem[w * 256 + (quad * 4 + r) * 16 + cL] = a0[r] + a1[r];
      __syncthreads();
      const int r = tid >> 4, c = tid & 15;
      const int b = rg * 16 + r, d = dg * 16 + c;
      const float gi = smem[0 * 256 + r * 16 + c] + b1sum[d];
      const float gf = smem[1 * 256 + r * 16 + c] + b1sum[1024 + d];
      const float gg = smem[2 * 256 + r * 16 + c] + b1sum[2048 + d];
      const float go = smem[3 * 256 + r * 16 + c] + b1sum[3072 + d];
      const size_t ci = (size_t)b * 1024 + d;
      const float cn = sigmoidf_(gf) * c1s[ci] + sigmoidf_(gi) * tanhf(gg);
      const float h  = sigmoidf_(go) * tanhf(cn);
      c1s[ci] = cn;
      stvh(h1W + ci, f2bf(h));
      stvf(h1f + ci, h);
    }
    grid_barrier(bar, ++gen, bi);

    // ---------- C': scores+softmax (blocks 0-63) | qh GEMM (64-127) -------
    if (bi < 64) {
      scores_softmax(bi, h1f, ctx2, alignG, outA + (size_t)t * 4096, tid, smem);
    } else if (bi < 128) {
      const int cg = bi - 64;
      const u16* ap = h1W + (size_t)(w * 16 + cL) * 1024 + quad * 8;  // fresh, nt
      const u16* bp = WoutHb + (size_t)(cg * 16 + cL) * 1024 + quad * 8;
      f32x4 a0 = {0,0,0,0}, a1 = {0,0,0,0};
      #pragma unroll 4
      for (int kc = 0; kc < 1024; kc += 64) {
        bf16x8 av0 = ldnt(ap);
        bf16x8 bv0 = *(const bf16x8*)bp;
        bf16x8 av1 = ldnt(ap + 32);
        bf16x8 bv1 = *(const bf16x8*)(bp + 32);
        ap += 64; bp += 64;
        a0 = __builtin_amdgcn_mfma_f32_16x16x32_bf16(av0, bv0, a0, 0, 0, 0);
        a1 = __builtin_amdgcn_mfma_f32_16x16x32_bf16(av1, bv1, a1, 0, 0, 0);
      }
      #pragma unroll
      for (int r = 0; r < 4; ++r)
        stvf(qh + (size_t)(w * 16 + quad * 4 + r) * 1024 + cg * 16 + cL,
             a0[r] + a1[r]);
    }
    grid_barrier(bar, ++gen, bi);

    // ---------------- D': attn_h = tanh(qh + sum_s align*ctx3) ------------
    {
      const int b = bi >> 2, dc = bi & 3;
      const int d = dc * 256 + tid;
      if (tid < 64) smem[tid] = ldvf(alignG + b * 64 + tid);
      __syncthreads();
      float acc = ldvf(qh + (size_t)b * 1024 + d);
      const u16* cp = ctx3 + (size_t)b * 1024 + d;   // L2-resident, read-only
      #pragma unroll 8
      for (int s = 0; s < 64; ++s)
        acc += smem[s] * bf2f(cp[(size_t)s * 65536]);
      const float v = tanhf(acc);
      __builtin_nontemporal_store(v, out + (size_t)t * 65536 + (size_t)b * 1024 + d);
      stvh(attnW + (size_t)b * 1024 + d, f2bf(v));
    }
    grid_barrier(bar, ++gen, bi);
  }
}

extern "C" void kernel_launch(void* const* d_in, const int* in_sizes, int n_in,
                              void* d_out, int out_size, void* d_ws, size_t ws_size,
                              hipStream_t stream)
{
  const float* emb   = (const float*)d_in[0];
  const float* ctx   = (const float*)d_in[1];
  const float* feed0 = (const float*)d_in[2];
  const float* h0    = (const float*)d_in[3];
  const float* c0    = (const float*)d_in[4];
  const float* Wih0  = (const float*)d_in[5];
  const float* Whh0  = (const float*)d_in[6];
  const float* bih0  = (const float*)d_in[7];
  const float* bhh0  = (const float*)d_in[8];
  const float* Wih1  = (const float*)d_in[9];
  const float* Whh1  = (const float*)d_in[10];
  const float* bih1  = (const float*)d_in[11];
  const float* bih1b = (const float*)d_in[12];
  const float* Win   = (const float*)d_in[13];
  const float* WoutW = (const float*)d_in[14];
  float* out = (float*)d_out;

  char* w = (char*)d_ws;
  u16*   Wg0p   = (u16*)(w + 0);            // 4096x3072 bf16; rot slots after preload
  u16*   Wg1p   = (u16*)(w + 25165824);     // 4096x2048
  u16*   WoutCb = (u16*)(w + 41943040);     // 1024x1024 (dead after prep GEMMs)
  u16*   WoutHb = (u16*)(w + 44040192);     // 1024x1024 (live)
  u16*   WinT   = (u16*)(w + 46137344);     // 1024x1024 (dead after prep GEMMs)
  u16*   ctxb   = (u16*)(w + 48234496);     // 4096x1024 (dead after prep GEMMs)
  u16*   ctx2   = (u16*)(w + 56623104);     // 4096x1024 (live)
  u16*   ctx3   = (u16*)(w + 65011712);     // 4096x1024 (live)
  u16*   init0  = (u16*)(w + 73400320);     // 3 x 64x1024 bf16 slot-0 states
  float* h1f    = (float*)(w + 73793536);   // 64x1024
  float* c0s    = (float*)(w + 74055680);   // 64x1024
  float* c1s    = (float*)(w + 74317824);   // 64x1024 (contiguous after c0s)
  float* qh     = (float*)(w + 74579968);   // 64x1024
  float* alignG = (float*)(w + 74842112);   // 64x64
  float* b0sum  = (float*)(w + 74858496);   // 4096
  float* b1sum  = (float*)(w + 74874880);   // 4096
  // embB overlays ctxb (dead after the prep GEMMs; k_init fills it afterwards
  // in stream order). Barrier flags overlay WinT (also dead; k_init zeroes).
  u16* embB = (u16*)(w + 48234496);         // 64x64x1024 bf16
  unsigned int* bar = (unsigned int*)(w + 46137344);

  k_prep<<<110624, 256, 0, stream>>>(Wih0, Whh0, Wih1, Whh1, WoutW, Win, ctx,
                                     bih0, bhh0, bih1, bih1b,
                                     Wg0p, Wg1p, WoutCb, WoutHb, WinT, ctxb,
                                     b0sum, b1sum);
  k_gemm1k<<<dim3(16, 64), 256, 0, stream>>>(ctxb, WinT, ctx2);
  k_gemm1k<<<dim3(16, 64), 256, 0, stream>>>(ctxb, WoutCb, ctx3);
  k_init<<<17681, 256, 0, stream>>>(emb, feed0, h0, c0, embB, init0, c0s, bar);

  k_persist<<<256, 256, 0, stream>>>(Wg0p, Wg1p, WoutHb, ctx2, ctx3,
                                     b0sum, b1sum, embB, init0,
                                     h1f, c0s, c1s, qh, alignG, bar,
                                     out, out + 4194304);
}

// Round 5
// 4411.538 us; speedup vs baseline: 1.3520x; 1.3520x over previous
//
#include <hip/hip_runtime.h>

// T=64, B=64, S=64, E=1024, D=1024, L=2
// Persistent-kernel schedule per step t (4 device-wide barriers):
//   A : gates0 = [attn_h|emb_t|h0prev](K=3072)·Wg0p^T + b0sum -> pointwise -> h0
//   B : gates1 = [h0|h1prev](K=2048)·Wg1p^T + b1sum -> pointwise -> h1
//   C': scores = h1f·ctx2 (per-b), softmax -> align ; qh = h1·WoutH^T
//   D': attn_h = tanh(qh + sum_s align*ctx3[s,b,:])
//
// Round-5 revision:
//  - REVERT round-4's nt loads on rotated activations/emb (they killed the
//    intra-XCD L2 dedup: nt doesn't allocate on miss, so 8-32 blocks/XCD each
//    made their own MALL round trip -> +20% time). Plain loads restore
//    first-reader-allocates / rest-hit-L2.
//  - Phase-B weights: first K-half (128 KB/block) staged ONCE into LDS in
//    per-lane fragment order (conflict-free ds_read_b128); second K-half
//    streams from a now-resident 1 MB/XCD L2 slice. Per-XCD resident set
//    drops to ~3.25 MB < 4 MiB -> B stops re-streaming weights every step.
//  - nt retained ONLY for: one-shot weight preload/staging reads, out stores.
//  - embB pre-convert kept (same f2bf rounding -> bit-identical).
// MFMA order/pairing unchanged -> bit-identical numerics.

typedef __attribute__((ext_vector_type(8))) short bf16x8;
typedef __attribute__((ext_vector_type(4))) float f32x4;
typedef unsigned short u16;
typedef unsigned long long u64;

__device__ __forceinline__ float bf2f(u16 u) {
  return __uint_as_float(((unsigned int)u) << 16);
}
__device__ __forceinline__ u16 f2bf(float f) {
  unsigned int u = __float_as_uint(f);
  u += 0x7FFFu + ((u >> 16) & 1u);
  return (u16)(u >> 16);
}
__device__ __forceinline__ float sigmoidf_(float x) { return 1.0f / (1.0f + expf(-x)); }

// volatile (bypass) accessors for cross-XCD one-way data
__device__ __forceinline__ float ldvf(const float* p) { return *(const volatile float*)p; }
__device__ __forceinline__ void stvh(u16* p, u16 v) { *(volatile u16*)p = v; }
__device__ __forceinline__ void stvf(float* p, float v) { *(volatile float*)p = v; }

// non-temporal 16B load (evict-first; one-shot reads only)
__device__ __forceinline__ bf16x8 ldnt(const u16* p) {
  f32x4 v = __builtin_nontemporal_load((const f32x4*)p);
  union { f32x4 f; bf16x8 b; } u; u.f = v; return u.b;
}

// ---------------- one-time: pack weights/context to bf16, bias sums --------
__global__ __launch_bounds__(256) void k_prep(
    const float* __restrict__ Wih0, const float* __restrict__ Whh0,
    const float* __restrict__ Wih1, const float* __restrict__ Whh1,
    const float* __restrict__ Wout, const float* __restrict__ Win,
    const float* __restrict__ ctx,
    const float* __restrict__ bih0, const float* __restrict__ bhh0,
    const float* __restrict__ bih1, const float* __restrict__ bhh1,
    u16* __restrict__ Wg0p, u16* __restrict__ Wg1p,
    u16* __restrict__ WoutCb, u16* __restrict__ WoutHb,
    u16* __restrict__ WinT, u16* __restrict__ ctxb,
    float* __restrict__ b0sum, float* __restrict__ b1sum)
{
  long i = (long)blockIdx.x * 256 + threadIdx.x;
  const long N0 = 4096L * 3072, N1 = 4096L * 2048, NM = 1024L * 1024,
             NC = 4194304L;
  if (i < N0) {  // Wg0p rows gd: [Wih0_feed | Wih0_emb | Whh0]
    long j = i / 3072, k = i % 3072;
    float v = (k < 1024) ? Wih0[j * 2048 + 1024 + k]
            : (k < 2048) ? Wih0[j * 2048 + (k - 1024)]
                         : Whh0[j * 1024 + (k - 2048)];
    Wg0p[i] = f2bf(v); return;
  }
  i -= N0;
  if (i < N1) {  // Wg1p rows gd: [Wih1 | Whh1]
    long j = i / 2048, k = i % 2048;
    float v = (k < 1024) ? Wih1[j * 1024 + k] : Whh1[j * 1024 + (k - 1024)];
    Wg1p[i] = f2bf(v); return;
  }
  i -= N1;
  if (i < NM) { long d = i >> 10, e = i & 1023; WoutCb[i] = f2bf(Wout[d * 2048 + e]); return; }
  i -= NM;
  if (i < NM) { long d = i >> 10, e = i & 1023; WoutHb[i] = f2bf(Wout[d * 2048 + 1024 + e]); return; }
  i -= NM;
  if (i < NM) { long e = i >> 10, d = i & 1023; WinT[i] = f2bf(Win[d * 1024 + e]); return; }
  i -= NM;
  if (i < NC) { ctxb[i] = f2bf(ctx[i]); return; }
  i -= NC;
  if (i < 4096) { b0sum[i] = bih0[i] + bhh0[i]; return; }
  i -= 4096;
  if (i < 4096) { b1sum[i] = bih1[i] + bhh1[i]; }
}

// ---------------- one-time: C[m][n] = sum_k A[m][k]*B[n][k], M=4096,N=1024,K=1024
__global__ __launch_bounds__(256) void k_gemm1k(
    const u16* __restrict__ A, const u16* __restrict__ Bm, u16* __restrict__ Cm)
{
  const int lane = threadIdx.x & 63, wv = threadIdx.x >> 6;
  const int quad = lane >> 4, cL = lane & 15;
  const int n0 = blockIdx.x * 64;
  const int m0 = blockIdx.y * 64 + wv * 16;
  f32x4 a0 = {0,0,0,0}, a1 = {0,0,0,0}, a2 = {0,0,0,0}, a3 = {0,0,0,0};
  const u16* ap  = A  + (size_t)(m0 + cL) * 1024 + quad * 8;
  const u16* bp0 = Bm + (size_t)(n0 +  0 + cL) * 1024 + quad * 8;
  const u16* bp1 = Bm + (size_t)(n0 + 16 + cL) * 1024 + quad * 8;
  const u16* bp2 = Bm + (size_t)(n0 + 32 + cL) * 1024 + quad * 8;
  const u16* bp3 = Bm + (size_t)(n0 + 48 + cL) * 1024 + quad * 8;
  #pragma unroll 4
  for (int kc = 0; kc < 1024; kc += 32) {
    bf16x8 a  = *(const bf16x8*)ap;  ap  += 32;
    bf16x8 b0 = *(const bf16x8*)bp0; bp0 += 32;
    bf16x8 b1 = *(const bf16x8*)bp1; bp1 += 32;
    bf16x8 b2 = *(const bf16x8*)bp2; bp2 += 32;
    bf16x8 b3 = *(const bf16x8*)bp3; bp3 += 32;
    a0 = __builtin_amdgcn_mfma_f32_16x16x32_bf16(a, b0, a0, 0, 0, 0);
    a1 = __builtin_amdgcn_mfma_f32_16x16x32_bf16(a, b1, a1, 0, 0, 0);
    a2 = __builtin_amdgcn_mfma_f32_16x16x32_bf16(a, b2, a2, 0, 0, 0);
    a3 = __builtin_amdgcn_mfma_f32_16x16x32_bf16(a, b3, a3, 0, 0, 0);
  }
  #pragma unroll
  for (int r = 0; r < 4; ++r) {
    size_t base = (size_t)(m0 + quad * 4 + r) * 1024;
    Cm[base + n0 +  0 + cL] = f2bf(a0[r]);
    Cm[base + n0 + 16 + cL] = f2bf(a1[r]);
    Cm[base + n0 + 32 + cL] = f2bf(a2[r]);
    Cm[base + n0 + 48 + cL] = f2bf(a3[r]);
  }
}

// ---------------- one-time: embB, initial slot-0 state, barrier reset ------
__global__ __launch_bounds__(256) void k_init(
    const float* __restrict__ emb, const float* __restrict__ feed0,
    const float* __restrict__ h0, const float* __restrict__ c0,
    u16* __restrict__ embB, u16* __restrict__ init0,
    float* __restrict__ cst, unsigned int* __restrict__ bar)
{
  long i = (long)blockIdx.x * 256 + threadIdx.x;
  if (i < 4194304) { embB[i] = f2bf(emb[i]); return; }   // emb -> bf16 (same rounding)
  i -= 4194304;
  if (i < 65536) { init0[i] = f2bf(feed0[i]); return; }               // attn slot0
  i -= 65536;
  if (i < 65536) { init0[65536 + i] = f2bf(h0[i]); return; }          // h0 slot0
  i -= 65536;
  if (i < 65536) { init0[131072 + i] = f2bf(h0[65536 + i]); return; } // h1 slot0
  i -= 65536;
  if (i < 131072) { cst[i] = c0[i]; return; }   // c0s,c1s contiguous
  i -= 131072;
  if (i < 4352) bar[i] = 0;   // release word + 256 arrival lines
}

// ---------------- device-wide barrier: relaxed flags, NO fences ------------
// bar[0] = release word; bar[16 + i*16] = arrival of block i.
// __syncthreads drains vmcnt(0) per wave before the arrival store, so all
// volatile (write-through) stores reached the coherence point; readers use
// bypass or cold-address loads -> no acquire-invalidate needed.
__device__ __forceinline__ void grid_barrier(unsigned int* bar, unsigned int gen,
                                             int bi) {
  __syncthreads();
  if (bi == 0) {
    if (threadIdx.x > 0) {
      while (__hip_atomic_load(&bar[16 + threadIdx.x * 16], __ATOMIC_RELAXED,
                               __HIP_MEMORY_SCOPE_AGENT) < gen)
        __builtin_amdgcn_s_sleep(1);
    }
    __syncthreads();
    if (threadIdx.x == 0)
      __hip_atomic_store(&bar[0], gen, __ATOMIC_RELAXED,
                         __HIP_MEMORY_SCOPE_AGENT);
  } else {
    if (threadIdx.x == 0) {
      __hip_atomic_store(&bar[16 + bi * 16], gen, __ATOMIC_RELAXED,
                         __HIP_MEMORY_SCOPE_AGENT);
      while (__hip_atomic_load(&bar[0], __ATOMIC_RELAXED,
                               __HIP_MEMORY_SCOPE_AGENT) < gen)
        __builtin_amdgcn_s_sleep(1);
    }
    __syncthreads();
  }
}

// ---------------- C' part 1: scores + softmax for one b --------------------
__device__ __forceinline__ void scores_softmax(
    int b, const float* __restrict__ h1f, const u16* __restrict__ ctx2,
    float* __restrict__ alignG, float* __restrict__ attnOut, int tid, float* smem)
{
  float* h1s = smem;          // [1024]
  float* red = smem + 1024;   // [256]
  for (int i = tid; i < 1024; i += 256) h1s[i] = ldvf(h1f + (size_t)b * 1024 + i);
  __syncthreads();
  {
    const int s = tid >> 2, pq = tid & 3;
    const u16* crow = ctx2 + (size_t)(s * 64 + b) * 1024 + pq * 256;  // L2-resident
    const float* hp = h1s + pq * 256;
    float part = 0.f;
    #pragma unroll 8
    for (int e = 0; e < 256; e += 4) {
      ushort4 cc = *(const ushort4*)(crow + e);
      part += hp[e] * bf2f(cc.x) + hp[e + 1] * bf2f(cc.y)
            + hp[e + 2] * bf2f(cc.z) + hp[e + 3] * bf2f(cc.w);
    }
    red[tid] = part;
  }
  __syncthreads();
  if (tid < 64) {
    float sc = red[tid * 4] + red[tid * 4 + 1] + red[tid * 4 + 2] + red[tid * 4 + 3];
    float mx = sc;
    for (int off = 32; off; off >>= 1) mx = fmaxf(mx, __shfl_xor(mx, off, 64));
    const float ex = expf(sc - mx);
    float sm = ex;
    for (int off = 32; off; off >>= 1) sm += __shfl_xor(sm, off, 64);
    const float a = ex / sm;
    stvf(alignG + b * 64 + tid, a);
    __builtin_nontemporal_store(a, attnOut + b * 64 + tid);  // external output
  }
}

// ---------------- the persistent kernel ------------------------------------
__global__ __launch_bounds__(256, 1) void k_persist(
    u16* WgRot,                       // Wg0p weights, then rotation slots (alias)
    const u16* __restrict__ Wg1p, const u16* __restrict__ WoutHb,
    const u16* __restrict__ ctx2, const u16* __restrict__ ctx3,
    const float* __restrict__ b0sum, const float* __restrict__ b1sum,
    const u16* __restrict__ embB, const u16* init0,
    float* h1f, float* c0s, float* c1s, float* qh, float* alignG,
    unsigned int* bar, float* out, float* outA)
{
  const int bi = blockIdx.x, tid = threadIdx.x;
  // XCD-aware remap: block bi sits on XCD (bi & 7); co-locate the 4 blocks
  // sharing a dg so each XCD L2 holds 1/8 of Wg1p-half/ctx2/ctx3/WoutH.
  const int rg = (bi >> 3) & 3;
  const int dg = ((bi & 7) << 3) | (bi >> 5);
  const int w = tid >> 6, lane = tid & 63, quad = lane >> 4, cL = lane & 15;
  __shared__ u16 wldsB[65536];       // Wg1p first K-half, per-lane fragment order
  __shared__ float smem[1280];
  unsigned int gen = 0;

  // Rotation slot bases (overlay the Wg0p region, 3 x 64 slots x 65536 u16):
  u16* rotA  = WgRot;             // attn_h slots 1..64
  u16* rotH0 = WgRot + 4194304;   // h0 slots 1..64
  u16* rotH1 = WgRot + 8388608;   // h1 slots 1..64

  // ---- stage Wg1p first K-half into LDS (once; nt: dead in L2 after) -----
  {
    u16* dst = wldsB + w * 16384 + lane * 8;
    const u16* src = Wg1p + (size_t)(w * 1024 + dg * 16 + cL) * 2048 + quad * 8;
    #pragma unroll
    for (int it = 0; it < 16; ++it) {
      *(bf16x8*)(dst + it * 1024)       = ldnt(src);
      *(bf16x8*)(dst + it * 1024 + 512) = ldnt(src + 32);
      src += 64;
    }
  }

  // ---- preload A-weights into registers (nt: don't seed L2) --------------
  bf16x8 wA0[48], wA1[48];
  {
    const u16* wp = WgRot + (size_t)(w * 1024 + dg * 16 + cL) * 3072 + quad * 8;
    #pragma unroll
    for (int j = 0; j < 48; ++j) {
      wA0[j] = ldnt(wp);
      wA1[j] = ldnt(wp + 32);
      wp += 64;
    }
  }
  // All preloads must complete before any block's rotation writes clobber Wg0p.
  grid_barrier(bar, ++gen, bi);

  for (int t = 0; t < 64; ++t) {
    const u16* attnR   = t ? rotA  + (size_t)(t - 1) * 65536 : init0;
    const u16* h0Rprev = t ? rotH0 + (size_t)(t - 1) * 65536 : init0 + 65536;
    const u16* h1Rprev = t ? rotH1 + (size_t)(t - 1) * 65536 : init0 + 131072;
    u16* h0W = rotH0 + (size_t)t * 65536;   // slot t+1 (written A, read B/A-next)
    u16* h1W = rotH1 + (size_t)t * 65536;   // slot t+1 (written B, read C'/B-next)
    u16* attnW = rotA + (size_t)t * 65536;  // slot t+1 (written D', read A-next)

    // ---------------- A: lstm0, weights in registers ----------------
    {
      const size_t rowOff = (size_t)(rg * 16 + cL);
      const u16* aAttn = attnR + rowOff * 1024 + quad * 8;
      const u16* aEmb = embB + (size_t)t * 65536 + rowOff * 1024 + quad * 8;
      const u16* aH0 = h0Rprev + rowOff * 1024 + quad * 8;
      f32x4 a0 = {0,0,0,0}, a1 = {0,0,0,0};
      #pragma unroll
      for (int j = 0; j < 16; ++j) {        // K 0..1023: attn_h (rotated, L2)
        bf16x8 av0 = *(const bf16x8*)(aAttn + j * 64);
        bf16x8 av1 = *(const bf16x8*)(aAttn + j * 64 + 32);
        a0 = __builtin_amdgcn_mfma_f32_16x16x32_bf16(av0, wA0[j], a0, 0, 0, 0);
        a1 = __builtin_amdgcn_mfma_f32_16x16x32_bf16(av1, wA1[j], a1, 0, 0, 0);
      }
      #pragma unroll
      for (int j = 0; j < 16; ++j) {        // K 1024..2047: emb (bf16, L2)
        bf16x8 av0 = *(const bf16x8*)(aEmb + j * 64);
        bf16x8 av1 = *(const bf16x8*)(aEmb + j * 64 + 32);
        a0 = __builtin_amdgcn_mfma_f32_16x16x32_bf16(av0, wA0[16 + j], a0, 0, 0, 0);
        a1 = __builtin_amdgcn_mfma_f32_16x16x32_bf16(av1, wA1[16 + j], a1, 0, 0, 0);
      }
      #pragma unroll
      for (int j = 0; j < 16; ++j) {        // K 2048..3071: h0prev (rotated, L2)
        bf16x8 av0 = *(const bf16x8*)(aH0 + j * 64);
        bf16x8 av1 = *(const bf16x8*)(aH0 + j * 64 + 32);
        a0 = __builtin_amdgcn_mfma_f32_16x16x32_bf16(av0, wA0[32 + j], a0, 0, 0, 0);
        a1 = __builtin_amdgcn_mfma_f32_16x16x32_bf16(av1, wA1[32 + j], a1, 0, 0, 0);
      }
      #pragma unroll
      for (int r = 0; r < 4; ++r)
        smem[w * 256 + (quad * 4 + r) * 16 + cL] = a0[r] + a1[r];
      __syncthreads();
      const int r = tid >> 4, c = tid & 15;
      const int b = rg * 16 + r, d = dg * 16 + c;
      const float gi = smem[0 * 256 + r * 16 + c] + b0sum[d];
      const float gf = smem[1 * 256 + r * 16 + c] + b0sum[1024 + d];
      const float gg = smem[2 * 256 + r * 16 + c] + b0sum[2048 + d];
      const float go = smem[3 * 256 + r * 16 + c] + b0sum[3072 + d];
      const size_t ci = (size_t)b * 1024 + d;
      const float cn = sigmoidf_(gf) * c0s[ci] + sigmoidf_(gi) * tanhf(gg);
      const float h  = sigmoidf_(go) * tanhf(cn);
      c0s[ci] = cn;                         // block-private, cached
      stvh(h0W + ci, f2bf(h));              // write-through to coherence point
    }
    grid_barrier(bar, ++gen, bi);

    // ---------------- B: lstm1 — LDS weights (K lo) + L2 weights (K hi) ---
    {
      const size_t rowOff = (size_t)(rg * 16 + cL);
      const u16* a0p = h0W + rowOff * 1024 + quad * 8;
      const u16* a1p = h1Rprev + rowOff * 1024 + quad * 8;
      const u16* wl = wldsB + w * 16384 + lane * 8;
      const u16* bp = Wg1p + (size_t)(w * 1024 + dg * 16 + cL) * 2048 + 1024 + quad * 8;
      f32x4 a0 = {0,0,0,0}, a1 = {0,0,0,0};
      #pragma unroll
      for (int it = 0; it < 16; ++it) {     // K 0..1023: h0, weights from LDS
        bf16x8 av0 = *(const bf16x8*)a0p;
        bf16x8 bv0 = *(const bf16x8*)(wl + it * 1024);
        bf16x8 av1 = *(const bf16x8*)(a0p + 32);
        bf16x8 bv1 = *(const bf16x8*)(wl + it * 1024 + 512);
        a0p += 64;
        a0 = __builtin_amdgcn_mfma_f32_16x16x32_bf16(av0, bv0, a0, 0, 0, 0);
        a1 = __builtin_amdgcn_mfma_f32_16x16x32_bf16(av1, bv1, a1, 0, 0, 0);
      }
      #pragma unroll 4
      for (int kc = 0; kc < 1024; kc += 64) {   // K 1024..2047: h1prev, L2 wts
        bf16x8 av0 = *(const bf16x8*)a1p;
        bf16x8 bv0 = *(const bf16x8*)bp;
        bf16x8 av1 = *(const bf16x8*)(a1p + 32);
        bf16x8 bv1 = *(const bf16x8*)(bp + 32);
        a1p += 64; bp += 64;
        a0 = __builtin_amdgcn_mfma_f32_16x16x32_bf16(av0, bv0, a0, 0, 0, 0);
        a1 = __builtin_amdgcn_mfma_f32_16x16x32_bf16(av1, bv1, a1, 0, 0, 0);
      }
      #pragma unroll
      for (int r = 0; r < 4; ++r)
        smem[w * 256 + (quad * 4 + r) * 16 + cL] = a0[r] + a1[r];
      __syncthreads();
      const int r = tid >> 4, c = tid & 15;
      const int b = rg * 16 + r, d = dg * 16 + c;
      const float gi = smem[0 * 256 + r * 16 + c] + b1sum[d];
      const float gf = smem[1 * 256 + r * 16 + c] + b1sum[1024 + d];
      const float gg = smem[2 * 256 + r * 16 + c] + b1sum[2048 + d];
      const float go = smem[3 * 256 + r * 16 + c] + b1sum[3072 + d];
      const size_t ci = (size_t)b * 1024 + d;
      const float cn = sigmoidf_(gf) * c1s[ci] + sigmoidf_(gi) * tanhf(gg);
      const float h  = sigmoidf_(go) * tanhf(cn);
      c1s[ci] = cn;
      stvh(h1W + ci, f2bf(h));
      stvf(h1f + ci, h);
    }
    grid_barrier(bar, ++gen, bi);

    // ---------- C': scores+softmax (blocks 0-63) | qh GEMM (64-127) -------
    if (bi < 64) {
      scores_softmax(bi, h1f, ctx2, alignG, outA + (size_t)t * 4096, tid, smem);
    } else if (bi < 128) {
      const int cg = bi - 64;
      const u16* ap = h1W + (size_t)(w * 16 + cL) * 1024 + quad * 8;
      const u16* bp = WoutHb + (size_t)(cg * 16 + cL) * 1024 + quad * 8;
      f32x4 a0 = {0,0,0,0}, a1 = {0,0,0,0};
      #pragma unroll 4
      for (int kc = 0; kc < 1024; kc += 64) {
        bf16x8 av0 = *(const bf16x8*)ap;
        bf16x8 bv0 = *(const bf16x8*)bp;
        bf16x8 av1 = *(const bf16x8*)(ap + 32);
        bf16x8 bv1 = *(const bf16x8*)(bp + 32);
        ap += 64; bp += 64;
        a0 = __builtin_amdgcn_mfma_f32_16x16x32_bf16(av0, bv0, a0, 0, 0, 0);
        a1 = __builtin_amdgcn_mfma_f32_16x16x32_bf16(av1, bv1, a1, 0, 0, 0);
      }
      #pragma unroll
      for (int r = 0; r < 4; ++r)
        stvf(qh + (size_t)(w * 16 + quad * 4 + r) * 1024 + cg * 16 + cL,
             a0[r] + a1[r]);
    }
    grid_barrier(bar, ++gen, bi);

    // ---------------- D': attn_h = tanh(qh + sum_s align*ctx3) ------------
    {
      const int b = bi >> 2, dc = bi & 3;
      const int d = dc * 256 + tid;
      if (tid < 64) smem[tid] = ldvf(alignG + b * 64 + tid);
      __syncthreads();
      float acc = ldvf(qh + (size_t)b * 1024 + d);
      const u16* cp = ctx3 + (size_t)b * 1024 + d;   // L2-resident, read-only
      #pragma unroll 8
      for (int s = 0; s < 64; ++s)
        acc += smem[s] * bf2f(cp[(size_t)s * 65536]);
      const float v = tanhf(acc);
      __builtin_nontemporal_store(v, out + (size_t)t * 65536 + (size_t)b * 1024 + d);
      stvh(attnW + (size_t)b * 1024 + d, f2bf(v));
    }
    grid_barrier(bar, ++gen, bi);
  }
}

extern "C" void kernel_launch(void* const* d_in, const int* in_sizes, int n_in,
                              void* d_out, int out_size, void* d_ws, size_t ws_size,
                              hipStream_t stream)
{
  const float* emb   = (const float*)d_in[0];
  const float* ctx   = (const float*)d_in[1];
  const float* feed0 = (const float*)d_in[2];
  const float* h0    = (const float*)d_in[3];
  const float* c0    = (const float*)d_in[4];
  const float* Wih0  = (const float*)d_in[5];
  const float* Whh0  = (const float*)d_in[6];
  const float* bih0  = (const float*)d_in[7];
  const float* bhh0  = (const float*)d_in[8];
  const float* Wih1  = (const float*)d_in[9];
  const float* Whh1  = (const float*)d_in[10];
  const float* bih1  = (const float*)d_in[11];
  const float* bhh1  = (const float*)d_in[12];
  const float* Win   = (const float*)d_in[13];
  const float* WoutW = (const float*)d_in[14];
  float* out = (float*)d_out;

  char* w = (char*)d_ws;
  u16*   Wg0p   = (u16*)(w + 0);            // 4096x3072 bf16; rot slots after preload
  u16*   Wg1p   = (u16*)(w + 25165824);     // 4096x2048
  u16*   WoutCb = (u16*)(w + 41943040);     // 1024x1024 (dead after prep GEMMs)
  u16*   WoutHb = (u16*)(w + 44040192);     // 1024x1024 (live)
  u16*   WinT   = (u16*)(w + 46137344);     // 1024x1024 (dead after prep GEMMs)
  u16*   ctxb   = (u16*)(w + 48234496);     // 4096x1024 (dead after prep GEMMs)
  u16*   ctx2   = (u16*)(w + 56623104);     // 4096x1024 (live)
  u16*   ctx3   = (u16*)(w + 65011712);     // 4096x1024 (live)
  u16*   init0  = (u16*)(w + 73400320);     // 3 x 64x1024 bf16 slot-0 states
  float* h1f    = (float*)(w + 73793536);   // 64x1024
  float* c0s    = (float*)(w + 74055680);   // 64x1024
  float* c1s    = (float*)(w + 74317824);   // 64x1024 (contiguous after c0s)
  float* qh     = (float*)(w + 74579968);   // 64x1024
  float* alignG = (float*)(w + 74842112);   // 64x64
  float* b0sum  = (float*)(w + 74858496);   // 4096
  float* b1sum  = (float*)(w + 74874880);   // 4096
  // embB overlays ctxb (dead after the prep GEMMs; k_init fills it afterwards
  // in stream order). Barrier flags overlay WinT (also dead; k_init zeroes).
  u16* embB = (u16*)(w + 48234496);         // 64x64x1024 bf16
  unsigned int* bar = (unsigned int*)(w + 46137344);

  k_prep<<<110624, 256, 0, stream>>>(Wih0, Whh0, Wih1, Whh1, WoutW, Win, ctx,
                                     bih0, bhh0, bih1, bhh1,
                                     Wg0p, Wg1p, WoutCb, WoutHb, WinT, ctxb,
                                     b0sum, b1sum);
  k_gemm1k<<<dim3(16, 64), 256, 0, stream>>>(ctxb, WinT, ctx2);
  k_gemm1k<<<dim3(16, 64), 256, 0, stream>>>(ctxb, WoutCb, ctx3);
  k_init<<<17681, 256, 0, stream>>>(emb, feed0, h0, c0, embB, init0, c0s, bar);

  k_persist<<<256, 256, 0, stream>>>(Wg0p, Wg1p, WoutHb, ctx2, ctx3,
                                     b0sum, b1sum, embB, init0,
                                     h1f, c0s, c1s, qh, alignG, bar,
                                     out, out + 4194304);
}